// Round 1
// baseline (2687.451 us; speedup 1.0000x reference)
//
#include <hip/hip_runtime.h>
#include <math.h>

// Problem constants
#define B_   32
#define L_   2048
#define D_   512
#define M_   32          // modes
#define BLROWS (B_*L_)   // 65536
#define NBIG ((size_t)BLROWS * D_)   // 33554432 elements

// ---------------------------------------------------------------------------
// Twiddle tables.  Twc[l][m] = cos(2*pi*m*l/L), Tws[l][m] = -sin(2*pi*m*l/L)
// (forward rfft sign).  Tb[l][2m]=cos, Tb[l][2m+1]=sin (inverse basis).
// Exact integer phase reduction keeps the argument in [0, 2*pi).
// ---------------------------------------------------------------------------
__global__ __launch_bounds__(256) void genTw(float* __restrict__ Twc,
                                             float* __restrict__ Tws) {
  int idx = blockIdx.x * 256 + threadIdx.x;   // l*32+m, 65536 total
  int l = idx >> 5, m = idx & 31;
  int r = (m * l) & (L_ - 1);
  float ang = (float)r * (6.283185307179586f / (float)L_);
  Twc[idx] = cosf(ang);
  Tws[idx] = -sinf(ang);
}

__global__ __launch_bounds__(256) void genTb(float* __restrict__ Tb) {
  int idx = blockIdx.x * 256 + threadIdx.x;   // l*64+j, 131072 total
  int l = idx >> 6, j = idx & 63;
  int m = j >> 1;
  int r = (m * l) & (L_ - 1);
  float ang = (float)r * (6.283185307179586f / (float)L_);
  Tb[idx] = (j & 1) ? sinf(ang) : cosf(ang);
}

// ---------------------------------------------------------------------------
// Generic fp32 GEMM:  C[r][c] = post( sum_k A[r][k]*W[c][k] + bias[c] ) (+resid)
// A: (M x K) row-major, W: (N x K) row-major (i.e. computes A @ W^T).
// BM=128, BN=64, BK=16, 256 threads, 8x4 per thread.
// ---------------------------------------------------------------------------
template <bool DO_GELU, bool DO_RESID>
__global__ __launch_bounds__(256) void gemm_nt(
    const float* __restrict__ A, const float* __restrict__ W,
    const float* __restrict__ bias, const float* __restrict__ resid,
    float* __restrict__ C, int M, int N, int K) {
  __shared__ float As[16][132];
  __shared__ float Bs[16][68];
  const int t = threadIdx.x;
  const int tx = t & 15, ty = t >> 4;
  const int row0 = blockIdx.x * 128, col0 = blockIdx.y * 64;

  float acc[8][4];
#pragma unroll
  for (int i = 0; i < 8; i++)
#pragma unroll
    for (int j = 0; j < 4; j++) acc[i][j] = 0.f;

  for (int k0 = 0; k0 < K; k0 += 16) {
#pragma unroll
    for (int s = 0; s < 2; s++) {
      int idx = t + s * 256;
      int arow = idx >> 2, kq = idx & 3;
      float4 av = *(const float4*)(A + (size_t)(row0 + arow) * K + k0 + kq * 4);
      As[kq * 4 + 0][arow] = av.x;
      As[kq * 4 + 1][arow] = av.y;
      As[kq * 4 + 2][arow] = av.z;
      As[kq * 4 + 3][arow] = av.w;
    }
    {
      int brow = t >> 2, kq = t & 3;
      float4 bv = *(const float4*)(W + (size_t)(col0 + brow) * K + k0 + kq * 4);
      Bs[kq * 4 + 0][brow] = bv.x;
      Bs[kq * 4 + 1][brow] = bv.y;
      Bs[kq * 4 + 2][brow] = bv.z;
      Bs[kq * 4 + 3][brow] = bv.w;
    }
    __syncthreads();
#pragma unroll
    for (int kk = 0; kk < 16; kk++) {
      float4 a0 = *(const float4*)&As[kk][ty * 8];
      float4 a1 = *(const float4*)&As[kk][ty * 8 + 4];
      float4 b0 = *(const float4*)&Bs[kk][tx * 4];
      float a[8] = {a0.x, a0.y, a0.z, a0.w, a1.x, a1.y, a1.z, a1.w};
      float b[4] = {b0.x, b0.y, b0.z, b0.w};
#pragma unroll
      for (int im = 0; im < 8; im++)
#pragma unroll
        for (int jn = 0; jn < 4; jn++) acc[im][jn] += a[im] * b[jn];
    }
    __syncthreads();
  }

  float bb[4] = {0.f, 0.f, 0.f, 0.f};
  if (bias != nullptr) {
    float4 bv = *(const float4*)(bias + col0 + tx * 4);
    bb[0] = bv.x; bb[1] = bv.y; bb[2] = bv.z; bb[3] = bv.w;
  }
#pragma unroll
  for (int im = 0; im < 8; im++) {
    size_t r = (size_t)row0 + ty * 8 + im;
    float o[4];
#pragma unroll
    for (int jn = 0; jn < 4; jn++) {
      float u = acc[im][jn] + bb[jn];
      if (DO_GELU) u = 0.5f * u * (1.0f + erff(u * 0.70710678118654752f));
      o[jn] = u;
    }
    float4 o4 = {o[0], o[1], o[2], o[3]};
    if (DO_RESID) {
      float4 rv = *(const float4*)(resid + r * N + col0 + tx * 4);
      o4.x += rv.x; o4.y += rv.y; o4.z += rv.z; o4.w += rv.w;
    }
    *(float4*)(C + r * N + col0 + tx * 4) = o4;
  }
}

// ---------------------------------------------------------------------------
// Stage B: forward DFT on kept modes.
// XFp_{r,i}[c][b][i][m] = sum over l in chunk c of q[b][l][i] * tw(m,l)
// grid (b=32, ig=8, c=2), 256 threads: lane=i within group, t>>6 = m-group (8 m)
// ---------------------------------------------------------------------------
__global__ __launch_bounds__(256) void stageB(
    const float* __restrict__ q, const float* __restrict__ Twc,
    const float* __restrict__ Tws, float* __restrict__ XFp_r,
    float* __restrict__ XFp_i) {
  __shared__ float qs[16][64];
  const int b = blockIdx.x, ig = blockIdx.y, c = blockIdx.z;
  const int t = threadIdx.x;
  const int lane = t & 63, mg = t >> 6;
  const int i0 = ig * 64;
  float ar[8], ai[8];
#pragma unroll
  for (int k = 0; k < 8; k++) { ar[k] = 0.f; ai[k] = 0.f; }
  const int lbase = c * 1024;

  for (int lt = 0; lt < 1024; lt += 16) {
#pragma unroll
    for (int s = 0; s < 4; s++) {
      int row = (t >> 6) + s * 4;
      qs[row][lane] =
          q[((size_t)b * L_ + lbase + lt + row) * D_ + i0 + lane];
    }
    __syncthreads();
#pragma unroll 4
    for (int l = 0; l < 16; l++) {
      float qv = qs[l][lane];
      int gl = lbase + lt + l;
      float4 c0 = *(const float4*)(Twc + gl * 32 + mg * 8);
      float4 c1 = *(const float4*)(Twc + gl * 32 + mg * 8 + 4);
      float4 s0 = *(const float4*)(Tws + gl * 32 + mg * 8);
      float4 s1 = *(const float4*)(Tws + gl * 32 + mg * 8 + 4);
      ar[0] += qv * c0.x; ar[1] += qv * c0.y; ar[2] += qv * c0.z; ar[3] += qv * c0.w;
      ar[4] += qv * c1.x; ar[5] += qv * c1.y; ar[6] += qv * c1.z; ar[7] += qv * c1.w;
      ai[0] += qv * s0.x; ai[1] += qv * s0.y; ai[2] += qv * s0.z; ai[3] += qv * s0.w;
      ai[4] += qv * s1.x; ai[5] += qv * s1.y; ai[6] += qv * s1.z; ai[7] += qv * s1.w;
    }
    __syncthreads();
  }
  size_t base = (((size_t)c * B_ + b) * D_ + i0 + lane) * 32 + mg * 8;
  float4 r0 = {ar[0], ar[1], ar[2], ar[3]}, r1 = {ar[4], ar[5], ar[6], ar[7]};
  float4 i0v = {ai[0], ai[1], ai[2], ai[3]}, i1v = {ai[4], ai[5], ai[6], ai[7]};
  *(float4*)(XFp_r + base) = r0;
  *(float4*)(XFp_r + base + 4) = r1;
  *(float4*)(XFp_i + base) = i0v;
  *(float4*)(XFp_i + base + 4) = i1v;
}

__global__ __launch_bounds__(256) void reduceXF(
    const float* __restrict__ XFp_r, const float* __restrict__ XFp_i,
    float* __restrict__ XF_r, float* __restrict__ XF_i) {
  const size_t CS = (size_t)B_ * D_ * 32;   // 524288
  size_t e = (size_t)blockIdx.x * 256 + threadIdx.x;
  if (e < CS) {
    XF_r[e] = XFp_r[e] + XFp_r[e + CS];
    XF_i[e] = XFp_i[e] + XFp_i[e + CS];
  }
}

// ---------------------------------------------------------------------------
// Stage C1: complex mode mix  OM[b][o][m] = sum_i XF[b][i][m] * Wf[i][o][m]
// grid (og=64, bg=4); thread: m = t&31, oq = t>>5 -> o = og*8+oq; 8 b's each.
// ---------------------------------------------------------------------------
__global__ __launch_bounds__(256) void stageC1(
    const float* __restrict__ XF_r, const float* __restrict__ XF_i,
    const float* __restrict__ WfR, const float* __restrict__ WfI,
    float* __restrict__ OM_r, float* __restrict__ OM_i) {
  const int m = threadIdx.x & 31, oq = threadIdx.x >> 5;
  const int o = blockIdx.x * 8 + oq;
  const int bg = blockIdx.y;
  float re[8], im[8];
#pragma unroll
  for (int r = 0; r < 8; r++) { re[r] = 0.f; im[r] = 0.f; }
  for (int i = 0; i < 512; i++) {
    float wr = WfR[((size_t)i * D_ + o) * 32 + m];
    float wi = WfI[((size_t)i * D_ + o) * 32 + m];
#pragma unroll
    for (int r = 0; r < 8; r++) {
      int b = bg * 8 + r;
      float xr_ = XF_r[((size_t)b * D_ + i) * 32 + m];
      float xi_ = XF_i[((size_t)b * D_ + i) * 32 + m];
      re[r] += xr_ * wr - xi_ * wi;
      im[r] += xr_ * wi + xi_ * wr;
    }
  }
#pragma unroll
  for (int r = 0; r < 8; r++) {
    size_t idx = ((size_t)(bg * 8 + r) * D_ + o) * 32 + m;
    OM_r[idx] = re[r];
    OM_i[idx] = im[r];
  }
}

// ---------------------------------------------------------------------------
// Stage C2: fold W_out:  G[b][d][m] = sum_o OM[b][o][m] * W_out[d][o],
// then write inverse-transform coefficients
//   CC[b][2m][d]   = alpha_m * Re(G)   (alpha_0 = 1/L, else 2/L)
//   CC[b][2m+1][d] = -(2/L) * Im(G)
// grid (b=32, mc=4, dc=2), thread = one d.
// ---------------------------------------------------------------------------
__global__ __launch_bounds__(256) void stageC2(
    const float* __restrict__ OM_r, const float* __restrict__ OM_i,
    const float* __restrict__ Wout, float* __restrict__ CC) {
  const int b = blockIdx.x, mc = blockIdx.y, dc = blockIdx.z;
  const int d = dc * 256 + threadIdx.x;
  float gr[8], gi[8];
#pragma unroll
  for (int k = 0; k < 8; k++) { gr[k] = 0.f; gi[k] = 0.f; }
  for (int o = 0; o < 512; o++) {
    float w = Wout[(size_t)d * D_ + o];
#pragma unroll
    for (int mm = 0; mm < 8; mm++) {
      int m = mc * 8 + mm;
      float omr = OM_r[((size_t)b * D_ + o) * 32 + m];
      float omi = OM_i[((size_t)b * D_ + o) * 32 + m];
      gr[mm] += omr * w;
      gi[mm] += omi * w;
    }
  }
#pragma unroll
  for (int mm = 0; mm < 8; mm++) {
    int m = mc * 8 + mm;
    float al = (m == 0) ? (1.f / (float)L_) : (2.f / (float)L_);
    CC[((size_t)b * 64 + 2 * m) * D_ + d] = al * gr[mm];
    CC[((size_t)b * 64 + 2 * m + 1) * D_ + d] = (-2.f / (float)L_) * gi[mm];
  }
}

// ---------------------------------------------------------------------------
// Stage D: xr_raw[b][l][d] = x[b][l][d] + b_out[d] + sum_j Tb[l][j]*CC[b][j][d]
// grid (b=32, lt=128): 16 l per block; wave wv handles 4 l's; lanes = 64 d.
// ---------------------------------------------------------------------------
__global__ __launch_bounds__(256) void stageD(
    const float* __restrict__ x, const float* __restrict__ Tb,
    const float* __restrict__ CC, const float* __restrict__ b_out,
    float* __restrict__ xr_raw) {
  __shared__ float Ts[16][64];
  const int b = blockIdx.x, lt = blockIdx.y;
  const int t = threadIdx.x, lane = t & 63, wv = t >> 6;
  const int l0 = lt * 16;
#pragma unroll
  for (int s = 0; s < 4; s++) {
    int idx = t + s * 256;
    int row = idx >> 6, j = idx & 63;
    Ts[row][j] = Tb[(size_t)(l0 + row) * 64 + j];
  }
  __syncthreads();
  for (int dc = 0; dc < 8; dc++) {
    int d = dc * 64 + lane;
    float bo = b_out[d];
    float a0 = x[((size_t)b * L_ + l0 + wv * 4 + 0) * D_ + d] + bo;
    float a1 = x[((size_t)b * L_ + l0 + wv * 4 + 1) * D_ + d] + bo;
    float a2 = x[((size_t)b * L_ + l0 + wv * 4 + 2) * D_ + d] + bo;
    float a3 = x[((size_t)b * L_ + l0 + wv * 4 + 3) * D_ + d] + bo;
#pragma unroll 8
    for (int j = 0; j < 64; j++) {
      float cc = CC[((size_t)b * 64 + j) * D_ + d];
      a0 += Ts[wv * 4 + 0][j] * cc;
      a1 += Ts[wv * 4 + 1][j] * cc;
      a2 += Ts[wv * 4 + 2][j] * cc;
      a3 += Ts[wv * 4 + 3][j] * cc;
    }
    xr_raw[((size_t)b * L_ + l0 + wv * 4 + 0) * D_ + d] = a0;
    xr_raw[((size_t)b * L_ + l0 + wv * 4 + 1) * D_ + d] = a1;
    xr_raw[((size_t)b * L_ + l0 + wv * 4 + 2) * D_ + d] = a2;
    xr_raw[((size_t)b * L_ + l0 + wv * 4 + 3) * D_ + d] = a3;
  }
}

// ---------------------------------------------------------------------------
// Stage E: series decomposition residual.
// out[l] = in[l] - (1/128) * sum_{t=l-64}^{l+63} in[clamp(t,0,L-1)]
// (torch replicate pad: front 64, end 63).  Rolling window per (b,d) column.
// grid (b=32, dg=2, lc=8): 256-l chunks with 128-load warmup.
// ---------------------------------------------------------------------------
__global__ __launch_bounds__(256) void stageE(const float* __restrict__ in,
                                              float* __restrict__ out) {
  const int b = blockIdx.x, dg = blockIdx.y, lc = blockIdx.z;
  const int d = dg * 256 + threadIdx.x;
  const float* col = in + (size_t)b * L_ * D_ + d;
  float* ocol = out + (size_t)b * L_ * D_ + d;
  const int l0 = lc * 256;
  float Wsum = 0.f;
  for (int s = l0 - 64; s < l0 + 64; s++) {
    int cl = min(max(s, 0), L_ - 1);
    Wsum += col[(size_t)cl * D_];
  }
  for (int l = l0; l < l0 + 256; l++) {
    float v = col[(size_t)l * D_];
    ocol[(size_t)l * D_] = v - Wsum * (1.f / 128.f);
    int fa = min(l + 64, L_ - 1);
    int fb = max(l - 64, 0);
    Wsum += col[(size_t)fa * D_] - col[(size_t)fb * D_];
  }
}

// ---------------------------------------------------------------------------
// BatchNorm over (b, d) per time step l.
// ---------------------------------------------------------------------------
__global__ __launch_bounds__(256) void bnStats(const float* __restrict__ res,
                                               float* __restrict__ meanb,
                                               float* __restrict__ rstdb) {
  const int l = blockIdx.x;
  const int t = threadIdx.x;
  float s = 0.f, s2 = 0.f;
  for (int b = 0; b < B_; b++) {
    const float* p = res + ((size_t)b * L_ + l) * D_;
    for (int d = t; d < D_; d += 256) {
      float v = p[d];
      s += v;
      s2 += v * v;
    }
  }
#pragma unroll
  for (int off = 32; off > 0; off >>= 1) {
    s += __shfl_down(s, off, 64);
    s2 += __shfl_down(s2, off, 64);
  }
  __shared__ float shs[4], shs2[4];
  int wid = t >> 6;
  if ((t & 63) == 0) { shs[wid] = s; shs2[wid] = s2; }
  __syncthreads();
  if (t == 0) {
    float S = shs[0] + shs[1] + shs[2] + shs[3];
    float S2 = shs2[0] + shs2[1] + shs2[2] + shs2[3];
    const float inv = 1.f / (float)(B_ * D_);
    float mean = S * inv;
    float var = S2 * inv - mean * mean;
    meanb[l] = mean;
    rstdb[l] = rsqrtf(var + 1e-5f);
  }
}

__global__ __launch_bounds__(256) void bnApply(
    const float* __restrict__ res, const float* __restrict__ gamma,
    const float* __restrict__ beta, const float* __restrict__ meanb,
    const float* __restrict__ rstdb, float* __restrict__ out) {
  size_t idx = (size_t)blockIdx.x * 256 + threadIdx.x;   // float4 index
  if (idx >= NBIG / 4) return;
  size_t e = idx * 4;
  int l = (int)((e >> 9) & (L_ - 1));
  float4 v = *(const float4*)(res + e);
  float m = meanb[l], rs = rstdb[l];
  float g = gamma[l] * rs, bt = beta[l];
  float4 o;
  o.x = (v.x - m) * g + bt;
  o.y = (v.y - m) * g + bt;
  o.z = (v.z - m) * g + bt;
  o.w = (v.w - m) * g + bt;
  *(float4*)(out + e) = o;
}

// ---------------------------------------------------------------------------
extern "C" void kernel_launch(void* const* d_in, const int* in_sizes, int n_in,
                              void* d_out, int out_size, void* d_ws,
                              size_t ws_size, hipStream_t stream) {
  const float* x      = (const float*)d_in[0];
  const float* W_in   = (const float*)d_in[1];
  const float* b_in   = (const float*)d_in[2];
  const float* Wf_r   = (const float*)d_in[3];
  const float* Wf_i   = (const float*)d_in[4];
  const float* W_out  = (const float*)d_in[5];
  const float* b_out  = (const float*)d_in[6];
  const float* W_c1   = (const float*)d_in[7];
  const float* W_c2   = (const float*)d_in[8];
  const float* gamma  = (const float*)d_in[9];
  const float* beta   = (const float*)d_in[10];
  float* outp = (float*)d_out;

  // workspace layout (floats)
  float* f = (float*)d_ws;
  float* buf0 = f;                       // NBIG: q -> xr -> res (in place)
  float* sm = f + NBIG;
  float* Twc  = sm;  sm += (size_t)L_ * 32;
  float* Tws  = sm;  sm += (size_t)L_ * 32;
  float* Tb   = sm;  sm += (size_t)L_ * 64;
  const size_t XFSZ = (size_t)B_ * D_ * 32;   // 524288
  float* XFp_r = sm; sm += 2 * XFSZ;
  float* XFp_i = sm; sm += 2 * XFSZ;
  float* XF_r  = sm; sm += XFSZ;
  float* XF_i  = sm; sm += XFSZ;
  float* OM_r  = sm; sm += XFSZ;
  float* OM_i  = sm; sm += XFSZ;
  float* CC    = sm; sm += (size_t)B_ * 64 * D_;
  float* meanb = sm; sm += L_;
  float* rstdb = sm; sm += L_;

  // tables
  genTw<<<256, 256, 0, stream>>>(Twc, Tws);
  genTb<<<512, 256, 0, stream>>>(Tb);

  // A: q = x @ W_in^T + b_in          -> buf0
  gemm_nt<false, false><<<dim3(BLROWS / 128, D_ / 64), 256, 0, stream>>>(
      x, W_in, b_in, nullptr, buf0, BLROWS, D_, D_);

  // B: forward DFT (32 modes) of q    -> XFp (2 l-chunks), reduce -> XF
  stageB<<<dim3(B_, 8, 2), 256, 0, stream>>>(buf0, Twc, Tws, XFp_r, XFp_i);
  reduceXF<<<(XFSZ + 255) / 256, 256, 0, stream>>>(XFp_r, XFp_i, XF_r, XF_i);

  // C1: complex mode mix              -> OM
  stageC1<<<dim3(64, 4), 256, 0, stream>>>(XF_r, XF_i, Wf_r, Wf_i, OM_r, OM_i);
  // C2: fold W_out, build inverse coefficients -> CC
  stageC2<<<dim3(B_, 4, 2), 256, 0, stream>>>(OM_r, OM_i, W_out, CC);

  // D: xr_raw = x + irfft-basis @ CC + b_out   -> d_out
  stageD<<<dim3(B_, L_ / 16), 256, 0, stream>>>(x, Tb, CC, b_out, outp);

  // E: xr = xr_raw - movavg(xr_raw,128)        -> buf0 (q dead)
  stageE<<<dim3(B_, 2, 8), 256, 0, stream>>>(outp, buf0);

  // F1: y1 = gelu(xr @ W_conv1^T)              -> d_out (xr_raw dead)
  gemm_nt<true, false><<<dim3(BLROWS / 128, D_ / 64), 256, 0, stream>>>(
      buf0, W_c1, nullptr, nullptr, outp, BLROWS, D_, D_);

  // F2: res = xr + y1 @ W_conv2^T              -> buf0 (in-place residual)
  gemm_nt<false, true><<<dim3(BLROWS / 128, D_ / 64), 256, 0, stream>>>(
      outp, W_c2, nullptr, buf0, buf0, BLROWS, D_, D_);

  // G: BatchNorm over (b, d) per l             -> d_out
  bnStats<<<L_, 256, 0, stream>>>(buf0, meanb, rstdb);
  bnApply<<<(NBIG / 4 + 255) / 256, 256, 0, stream>>>(buf0, gamma, beta, meanb,
                                                      rstdb, outp);
}

// Round 2
// 1064.270 us; speedup vs baseline: 2.5252x; 2.5252x over previous
//
#include <hip/hip_runtime.h>
#include <hip/hip_bf16.h>
#include <math.h>

#define B_   32
#define L_   2048
#define D_   512
#define BLROWS (B_*L_)                 // 65536
#define NBIG ((size_t)BLROWS * D_)     // 33554432

typedef __hip_bfloat16 bf16;
using bf16x8 = __attribute__((ext_vector_type(8))) short;
using f32x4  = __attribute__((ext_vector_type(4))) float;

__device__ __forceinline__ unsigned short f2b(float f) {
  bf16 h = __float2bfloat16(f);
  return *reinterpret_cast<unsigned short*>(&h);
}

__device__ __forceinline__ void gl_lds16(const void* g, void* l) {
  __builtin_amdgcn_global_load_lds(
      (const __attribute__((address_space(1))) void*)g,
      (__attribute__((address_space(3))) void*)l, 16, 0, 0);
}

// ---------------------------------------------------------------------------
// fp32 -> bf16 vectorized converter (also used for the three weight matrices)
// ---------------------------------------------------------------------------
__global__ __launch_bounds__(256) void f2bfK(const float4* __restrict__ src,
                                             ushort4* __restrict__ dst,
                                             size_t n4) {
  for (size_t i = (size_t)blockIdx.x * 256 + threadIdx.x; i < n4;
       i += (size_t)gridDim.x * 256) {
    float4 v = src[i];
    ushort4 o;
    o.x = f2b(v.x); o.y = f2b(v.y); o.z = f2b(v.z); o.w = f2b(v.w);
    dst[i] = o;
  }
}

// ---------------------------------------------------------------------------
// Twiddle tables.
// TwP[l][mg][j]: j<8 -> cos(2pi*m*l/L), j>=8 -> -sin(...), m = mg*8 + (j&7)
// Tbbf[l][2m] = cos, [2m+1] = sin (inverse basis, bf16)
// ---------------------------------------------------------------------------
__global__ __launch_bounds__(256) void genTwP(float* __restrict__ TwP) {
  int idx = blockIdx.x * 256 + threadIdx.x;   // l*64 + mg*16 + j ; 131072
  int l = idx >> 6, rem = idx & 63, mg = rem >> 4, j = rem & 15;
  int m = mg * 8 + (j & 7);
  int r = (m * l) & (L_ - 1);
  float ang = (float)r * (6.283185307179586f / (float)L_);
  TwP[idx] = (j < 8) ? cosf(ang) : -sinf(ang);
}

__global__ __launch_bounds__(256) void genTbBf(bf16* __restrict__ Tb) {
  int idx = blockIdx.x * 256 + threadIdx.x;   // l*64 + j ; 131072
  int l = idx >> 6, j = idx & 63;
  int m = j >> 1;
  int r = (m * l) & (L_ - 1);
  float ang = (float)r * (6.283185307179586f / (float)L_);
  float v = (j & 1) ? sinf(ang) : cosf(ang);
  Tb[idx] = __float2bfloat16(v);
}

// ---------------------------------------------------------------------------
// bf16 MFMA GEMM (m97 structure): C = post(A @ Wt^T + bias) (+resid)
// A: M x K bf16 row-major, Wt: N x K bf16 row-major.
// 128x128 tile, BK=32, 256 threads (4 waves 2x2), 16x16x32 MFMA.
// Batched via blockIdx.z with element strides batchA/batchB/batchC.
// ---------------------------------------------------------------------------
template <bool GELU, bool RESID, bool BIAS, bool OUTBF>
__global__ __launch_bounds__(256) void gemm_bt(
    const bf16* __restrict__ A, const bf16* __restrict__ Wt,
    const float* __restrict__ bias, const float* __restrict__ resid,
    void* __restrict__ Cout, int M, int N, int K,
    long batchA, long batchB, long batchC) {
  __shared__ __align__(16) bf16 As[128 * 32];
  __shared__ __align__(16) bf16 Bs[128 * 32];
  const int t = threadIdx.x;
  const int lane = t & 63;
  const int wid = t >> 6, wr = wid >> 1, wc = wid & 1;
  const int row0 = blockIdx.x * 128, col0 = blockIdx.y * 128;
  const int zb = blockIdx.z;
  A += (size_t)zb * (size_t)batchA;
  Wt += (size_t)zb * (size_t)batchB;
  const float* residp = nullptr;
  if (RESID) residp = resid + (size_t)zb * (size_t)batchC;

  f32x4 acc[4][4];
#pragma unroll
  for (int i = 0; i < 4; i++)
#pragma unroll
    for (int j = 0; j < 4; j++) acc[i][j] = (f32x4){0.f, 0.f, 0.f, 0.f};

  const int srow = t >> 2, scq = t & 3;      // staging row/chunk
  bf16* AsW0 = &As[(size_t)(t & ~63) * 8];
  bf16* AsW1 = &As[(size_t)(256 + (t & ~63)) * 8];
  bf16* BsW0 = &Bs[(size_t)(t & ~63) * 8];
  bf16* BsW1 = &Bs[(size_t)(256 + (t & ~63)) * 8];

  for (int k0 = 0; k0 < K; k0 += 32) {
    gl_lds16(A + (size_t)(row0 + srow) * K + k0 + scq * 8, AsW0);
    gl_lds16(A + (size_t)(row0 + 64 + srow) * K + k0 + scq * 8, AsW1);
    gl_lds16(Wt + (size_t)(col0 + srow) * K + k0 + scq * 8, BsW0);
    gl_lds16(Wt + (size_t)(col0 + 64 + srow) * K + k0 + scq * 8, BsW1);
    __syncthreads();
    bf16x8 af[4], bg[4];
#pragma unroll
    for (int m = 0; m < 4; m++)
      af[m] = *reinterpret_cast<const bf16x8*>(
          &As[(wr * 64 + m * 16 + (lane & 15)) * 32 + (lane >> 4) * 8]);
#pragma unroll
    for (int n = 0; n < 4; n++)
      bg[n] = *reinterpret_cast<const bf16x8*>(
          &Bs[(wc * 64 + n * 16 + (lane & 15)) * 32 + (lane >> 4) * 8]);
#pragma unroll
    for (int m = 0; m < 4; m++)
#pragma unroll
      for (int n = 0; n < 4; n++)
        acc[m][n] = __builtin_amdgcn_mfma_f32_16x16x32_bf16(af[m], bg[n],
                                                            acc[m][n], 0, 0, 0);
    __syncthreads();
  }

  float* Cf = (float*)Cout;
  bf16* Cb = (bf16*)Cout;
  const size_t cbase = (size_t)zb * (size_t)batchC;
#pragma unroll
  for (int n = 0; n < 4; n++) {
    int col = col0 + wc * 64 + n * 16 + (lane & 15);
    float bs = 0.f;
    if (BIAS) bs = bias[col];
#pragma unroll
    for (int m = 0; m < 4; m++) {
#pragma unroll
      for (int j = 0; j < 4; j++) {
        int row = row0 + wr * 64 + m * 16 + (lane >> 4) * 4 + j;
        float v = acc[m][n][j] + bs;
        if (GELU) v = 0.5f * v * (1.0f + erff(v * 0.70710678118654752f));
        if (RESID) v += residp[(size_t)row * N + col];
        size_t idx = cbase + (size_t)row * N + col;
        if (OUTBF) Cb[idx] = __float2bfloat16(v);
        else Cf[idx] = v;
      }
    }
  }
}

// ---------------------------------------------------------------------------
// Stage B: forward DFT on 32 kept modes, partial over l-chunks of 256.
// grid (b=32, ig=8, lc=8), 256 thr: lane = i within 64-group, mg = wave.
// Per-wave twiddle slice (128 l x 16 floats) staged in LDS via global_load_lds.
// ---------------------------------------------------------------------------
__global__ __launch_bounds__(256) void stageB(
    const bf16* __restrict__ q, const float* __restrict__ TwP,
    float* __restrict__ XFp_r, float* __restrict__ XFp_i) {
  __shared__ __align__(16) float Tls[4 * 128 * 16];   // 32 KB
  const int b = blockIdx.x, ig = blockIdx.y, lc = blockIdx.z;
  const int t = threadIdx.x, lane = t & 63, mg = t >> 6;
  const int i0 = ig * 64;
  float ar[8], ai[8];
#pragma unroll
  for (int k = 0; k < 8; k++) { ar[k] = 0.f; ai[k] = 0.f; }
  float* TlsW = &Tls[mg * 2048];

  for (int h = 0; h < 2; h++) {
    const int hb = lc * 256 + h * 128;
    // stage this wave's 8 KB twiddle slice: [128 l][16 floats]
#pragma unroll
    for (int s = 0; s < 8; s++) {
      int flat = s * 64 + lane;            // 0..511
      int l = flat >> 2, q4 = flat & 3;
      gl_lds16(TwP + ((size_t)(hb + l) * 4 + mg) * 16 + q4 * 4,
               TlsW + s * 256);
    }
    __syncthreads();
#pragma unroll 4
    for (int l = 0; l < 128; l++) {
      float qv = __bfloat162float(q[((size_t)b * L_ + hb + l) * D_ + i0 + lane]);
      const float* Tp = TlsW + l * 16;
      float4 c0 = *(const float4*)(Tp);
      float4 c1 = *(const float4*)(Tp + 4);
      float4 s0 = *(const float4*)(Tp + 8);
      float4 s1 = *(const float4*)(Tp + 12);
      ar[0] += qv * c0.x; ar[1] += qv * c0.y; ar[2] += qv * c0.z; ar[3] += qv * c0.w;
      ar[4] += qv * c1.x; ar[5] += qv * c1.y; ar[6] += qv * c1.z; ar[7] += qv * c1.w;
      ai[0] += qv * s0.x; ai[1] += qv * s0.y; ai[2] += qv * s0.z; ai[3] += qv * s0.w;
      ai[4] += qv * s1.x; ai[5] += qv * s1.y; ai[6] += qv * s1.z; ai[7] += qv * s1.w;
    }
    __syncthreads();
  }
  size_t base = (((size_t)lc * B_ + b) * D_ + i0 + lane) * 32 + mg * 8;
  float4 r0 = {ar[0], ar[1], ar[2], ar[3]}, r1 = {ar[4], ar[5], ar[6], ar[7]};
  float4 i0v = {ai[0], ai[1], ai[2], ai[3]}, i1v = {ai[4], ai[5], ai[6], ai[7]};
  *(float4*)(XFp_r + base) = r0;
  *(float4*)(XFp_r + base + 4) = r1;
  *(float4*)(XFp_i + base) = i0v;
  *(float4*)(XFp_i + base + 4) = i1v;
}

__global__ __launch_bounds__(256) void reduceXF(
    const float* __restrict__ XFp_r, const float* __restrict__ XFp_i,
    float* __restrict__ XF_r, float* __restrict__ XF_i) {
  const size_t CS = (size_t)B_ * D_ * 32;   // 524288
  size_t e = (size_t)blockIdx.x * 256 + threadIdx.x;
  float sr = 0.f, si = 0.f;
#pragma unroll
  for (int c = 0; c < 8; c++) {
    sr += XFp_r[c * CS + e];
    si += XFp_i[c * CS + e];
  }
  XF_r[e] = sr;
  XF_i[e] = si;
}

// ---------------------------------------------------------------------------
// Stage C1: complex mode mix  OM[b][o][m] = sum_i XF[b][i][m] * Wf[i][o][m]
// ---------------------------------------------------------------------------
__global__ __launch_bounds__(256) void stageC1(
    const float* __restrict__ XF_r, const float* __restrict__ XF_i,
    const float* __restrict__ WfR, const float* __restrict__ WfI,
    float* __restrict__ OM_r, float* __restrict__ OM_i) {
  const int m = threadIdx.x & 31, oq = threadIdx.x >> 5;
  const int o = blockIdx.x * 8 + oq;
  const int bg = blockIdx.y;
  float re[8], im[8];
#pragma unroll
  for (int r = 0; r < 8; r++) { re[r] = 0.f; im[r] = 0.f; }
  for (int i = 0; i < 512; i++) {
    float wr = WfR[((size_t)i * D_ + o) * 32 + m];
    float wi = WfI[((size_t)i * D_ + o) * 32 + m];
#pragma unroll
    for (int r = 0; r < 8; r++) {
      int b = bg * 8 + r;
      float xr_ = XF_r[((size_t)b * D_ + i) * 32 + m];
      float xi_ = XF_i[((size_t)b * D_ + i) * 32 + m];
      re[r] += xr_ * wr - xi_ * wi;
      im[r] += xr_ * wi + xi_ * wr;
    }
  }
#pragma unroll
  for (int r = 0; r < 8; r++) {
    size_t idx = ((size_t)(bg * 8 + r) * D_ + o) * 32 + m;
    OM_r[idx] = re[r];
    OM_i[idx] = im[r];
  }
}

// ---------------------------------------------------------------------------
// Stage C2: fold W_out and write transposed bf16 inverse coefficients
//   CCT[b][d][2m]   = alpha_m * Re(G),  CCT[b][d][2m+1] = -(2/L) * Im(G)
// ---------------------------------------------------------------------------
__global__ __launch_bounds__(256) void stageC2(
    const float* __restrict__ OM_r, const float* __restrict__ OM_i,
    const float* __restrict__ Wout, bf16* __restrict__ CCT) {
  const int b = blockIdx.x, mc = blockIdx.y, dc = blockIdx.z;
  const int d = dc * 256 + threadIdx.x;
  float gr[8], gi[8];
#pragma unroll
  for (int k = 0; k < 8; k++) { gr[k] = 0.f; gi[k] = 0.f; }
  for (int o = 0; o < 512; o++) {
    float w = Wout[(size_t)d * D_ + o];
#pragma unroll
    for (int mm = 0; mm < 8; mm++) {
      int m = mc * 8 + mm;
      float omr = OM_r[((size_t)b * D_ + o) * 32 + m];
      float omi = OM_i[((size_t)b * D_ + o) * 32 + m];
      gr[mm] += omr * w;
      gi[mm] += omi * w;
    }
  }
#pragma unroll
  for (int mm = 0; mm < 8; mm++) {
    int m = mc * 8 + mm;
    float al = (m == 0) ? (1.f / (float)L_) : (2.f / (float)L_);
    CCT[((size_t)b * D_ + d) * 64 + 2 * m] = __float2bfloat16(al * gr[mm]);
    CCT[((size_t)b * D_ + d) * 64 + 2 * m + 1] =
        __float2bfloat16((-2.f / (float)L_) * gi[mm]);
  }
}

// ---------------------------------------------------------------------------
// Stage E: series decomposition residual (rolling window, replicate pad 64/63)
// ---------------------------------------------------------------------------
__global__ __launch_bounds__(256) void stageE(const float* __restrict__ in,
                                              float* __restrict__ out) {
  const int b = blockIdx.x, dg = blockIdx.y, lc = blockIdx.z;
  const int d = dg * 256 + threadIdx.x;
  const float* col = in + (size_t)b * L_ * D_ + d;
  float* ocol = out + (size_t)b * L_ * D_ + d;
  const int l0 = lc * 256;
  float Wsum = 0.f;
  for (int s = l0 - 64; s < l0 + 64; s++) {
    int cl = min(max(s, 0), L_ - 1);
    Wsum += col[(size_t)cl * D_];
  }
  for (int l = l0; l < l0 + 256; l++) {
    float v = col[(size_t)l * D_];
    ocol[(size_t)l * D_] = v - Wsum * (1.f / 128.f);
    int fa = min(l + 64, L_ - 1);
    int fb = max(l - 64, 0);
    Wsum += col[(size_t)fa * D_] - col[(size_t)fb * D_];
  }
}

// ---------------------------------------------------------------------------
// BatchNorm over (b, d) per time step l.
// ---------------------------------------------------------------------------
__global__ __launch_bounds__(256) void bnStats(const float* __restrict__ res,
                                               float* __restrict__ meanb,
                                               float* __restrict__ rstdb) {
  const int l = blockIdx.x;
  const int t = threadIdx.x;
  float s = 0.f, s2 = 0.f;
  for (int b = 0; b < B_; b++) {
    const float* p = res + ((size_t)b * L_ + l) * D_;
    for (int d = t; d < D_; d += 256) {
      float v = p[d];
      s += v;
      s2 += v * v;
    }
  }
#pragma unroll
  for (int off = 32; off > 0; off >>= 1) {
    s += __shfl_down(s, off, 64);
    s2 += __shfl_down(s2, off, 64);
  }
  __shared__ float shs[4], shs2[4];
  int wid = t >> 6;
  if ((t & 63) == 0) { shs[wid] = s; shs2[wid] = s2; }
  __syncthreads();
  if (t == 0) {
    float S = shs[0] + shs[1] + shs[2] + shs[3];
    float S2 = shs2[0] + shs2[1] + shs2[2] + shs2[3];
    const float inv = 1.f / (float)(B_ * D_);
    float mean = S * inv;
    float var = S2 * inv - mean * mean;
    meanb[l] = mean;
    rstdb[l] = rsqrtf(var + 1e-5f);
  }
}

__global__ __launch_bounds__(256) void bnApply(
    const float* __restrict__ res, const float* __restrict__ gamma,
    const float* __restrict__ beta, const float* __restrict__ meanb,
    const float* __restrict__ rstdb, float* __restrict__ out) {
  size_t idx = (size_t)blockIdx.x * 256 + threadIdx.x;   // float4 index
  if (idx >= NBIG / 4) return;
  size_t e = idx * 4;
  int l = (int)((e >> 9) & (L_ - 1));
  float4 v = *(const float4*)(res + e);
  float m = meanb[l], rs = rstdb[l];
  float g = gamma[l] * rs, bt = beta[l];
  float4 o;
  o.x = (v.x - m) * g + bt;
  o.y = (v.y - m) * g + bt;
  o.z = (v.z - m) * g + bt;
  o.w = (v.w - m) * g + bt;
  *(float4*)(out + e) = o;
}

// ---------------------------------------------------------------------------
extern "C" void kernel_launch(void* const* d_in, const int* in_sizes, int n_in,
                              void* d_out, int out_size, void* d_ws,
                              size_t ws_size, hipStream_t stream) {
  const float* x      = (const float*)d_in[0];
  const float* W_in   = (const float*)d_in[1];
  const float* b_in   = (const float*)d_in[2];
  const float* Wf_r   = (const float*)d_in[3];
  const float* Wf_i   = (const float*)d_in[4];
  const float* W_out  = (const float*)d_in[5];
  const float* b_out  = (const float*)d_in[6];
  const float* W_c1   = (const float*)d_in[7];
  const float* W_c2   = (const float*)d_in[8];
  const float* gamma  = (const float*)d_in[9];
  const float* beta   = (const float*)d_in[10];
  float* outp = (float*)d_out;

  // ---- workspace layout (ws use ~137 MB) ----
  float* f = (float*)d_ws;
  float* buf0 = f;                                   // NBIG fp32 (xr -> res)
  // aliases inside buf0, all dead before stageE writes xr:
  float* XFp_r = buf0;                               // 8*524288
  float* XFp_i = XFp_r + (size_t)8 * 524288;
  float* XF_r  = XFp_i + (size_t)8 * 524288;
  float* XF_i  = XF_r + 524288;
  float* OM_r  = XF_i + 524288;
  float* OM_i  = OM_r + 524288;
  bf16*  CCT   = (bf16*)(OM_i + 524288);             // 32*512*64 bf16
  // tail after buf0:
  float* TwP   = f + NBIG;                           // 131072 f
  bf16*  Tbbf  = (bf16*)(TwP + 131072);              // 131072 bf16
  bf16*  Wibf  = Tbbf + 131072;                      // 262144 bf16 x3
  bf16*  W1bf  = Wibf + 262144;
  bf16*  W2bf  = W1bf + 262144;
  float* meanb = (float*)(W2bf + 262144);
  float* rstdb = meanb + L_;

  // d_out double-duty: [xbf | qbf] (2 x NBIG bf16 == exactly out bytes),
  // later xr_raw fp32 (full), later [y1bf | xrbf].
  bf16* xbf  = (bf16*)d_out;
  bf16* qbf  = xbf + NBIG;
  bf16* y1bf = (bf16*)d_out;
  bf16* xrbf = ((bf16*)d_out) + NBIG;

  // tables + dtype conversions
  genTwP<<<512, 256, 0, stream>>>(TwP);
  genTbBf<<<512, 256, 0, stream>>>(Tbbf);
  f2bfK<<<2048, 256, 0, stream>>>((const float4*)x, (ushort4*)xbf, NBIG / 4);
  f2bfK<<<256, 256, 0, stream>>>((const float4*)W_in, (ushort4*)Wibf, 65536);
  f2bfK<<<256, 256, 0, stream>>>((const float4*)W_c1, (ushort4*)W1bf, 65536);
  f2bfK<<<256, 256, 0, stream>>>((const float4*)W_c2, (ushort4*)W2bf, 65536);

  // A: q = x @ W_in^T + b_in  (bf16 out)
  gemm_bt<false, false, true, true><<<dim3(512, 4, 1), 256, 0, stream>>>(
      xbf, Wibf, b_in, nullptr, qbf, BLROWS, D_, D_, 0, 0, 0);

  // B: forward DFT partials + reduce
  stageB<<<dim3(B_, 8, 8), 256, 0, stream>>>(qbf, TwP, XFp_r, XFp_i);
  reduceXF<<<2048, 256, 0, stream>>>(XFp_r, XFp_i, XF_r, XF_i);

  // C: mode mix, fold W_out -> CCT (bf16, transposed)
  stageC1<<<dim3(64, 4), 256, 0, stream>>>(XF_r, XF_i, Wf_r, Wf_i, OM_r, OM_i);
  stageC2<<<dim3(B_, 4, 2), 256, 0, stream>>>(OM_r, OM_i, W_out, CCT);

  // D: xr_raw = x + b_out + Tb @ CCT^T   (batched MFMA, fp32 out -> d_out)
  gemm_bt<false, true, true, false><<<dim3(16, 4, 32), 256, 0, stream>>>(
      Tbbf, CCT, b_out, x, outp, L_, D_, 64, 0, (long)D_ * 64,
      (long)L_ * D_);

  // E: xr = xr_raw - movavg(xr_raw)  -> buf0 ; then bf16 copy -> xrbf
  stageE<<<dim3(B_, 2, 8), 256, 0, stream>>>(outp, buf0);
  f2bfK<<<2048, 256, 0, stream>>>((const float4*)buf0, (ushort4*)xrbf, NBIG / 4);

  // F1: y1 = gelu(xr @ Wc1^T)  (bf16 out)
  gemm_bt<true, false, false, true><<<dim3(512, 4, 1), 256, 0, stream>>>(
      xrbf, W1bf, nullptr, nullptr, y1bf, BLROWS, D_, D_, 0, 0, 0);

  // F2: res = xr + y1 @ Wc2^T  (fp32, in-place on buf0)
  gemm_bt<false, true, false, false><<<dim3(512, 4, 1), 256, 0, stream>>>(
      y1bf, W2bf, nullptr, buf0, buf0, BLROWS, D_, D_, 0, 0, 0);

  // G: BatchNorm over (b, d) per l
  bnStats<<<L_, 256, 0, stream>>>(buf0, meanb, rstdb);
  bnApply<<<(NBIG / 4 + 255) / 256, 256, 0, stream>>>(buf0, gamma, beta, meanb,
                                                      rstdb, outp);
}

// Round 4
// 837.232 us; speedup vs baseline: 3.2099x; 1.2712x over previous
//
#include <hip/hip_runtime.h>
#include <hip/hip_bf16.h>
#include <math.h>

#define B_   32
#define L_   2048
#define D_   512
#define BLROWS (B_*L_)                 // 65536
#define NBIG ((size_t)BLROWS * D_)     // 33554432

typedef __hip_bfloat16 bf16;
using bf16x8 = __attribute__((ext_vector_type(8))) short;
using f32x4  = __attribute__((ext_vector_type(4))) float;

__device__ __forceinline__ unsigned short f2b(float f) {
  bf16 h = __float2bfloat16(f);
  return *reinterpret_cast<unsigned short*>(&h);
}

__device__ __forceinline__ void gl_lds16(const void* g, void* l) {
  __builtin_amdgcn_global_load_lds(
      (const __attribute__((address_space(1))) void*)g,
      (__attribute__((address_space(3))) void*)l, 16, 0, 0);
}

// ---------------------------------------------------------------------------
// fp32 -> bf16 vectorized converter
// ---------------------------------------------------------------------------
__global__ __launch_bounds__(256) void f2bfK(const float4* __restrict__ src,
                                             ushort4* __restrict__ dst,
                                             size_t n4) {
  for (size_t i = (size_t)blockIdx.x * 256 + threadIdx.x; i < n4;
       i += (size_t)gridDim.x * 256) {
    float4 v = src[i];
    ushort4 o;
    o.x = f2b(v.x); o.y = f2b(v.y); o.z = f2b(v.z); o.w = f2b(v.w);
    dst[i] = o;
  }
}

// ---------------------------------------------------------------------------
// Twiddle tables.
// TwP[l][mg][j]: j<8 -> cos(2pi*m*l/L), j>=8 -> -sin(...), m = mg*8 + (j&7)
// Tbbf[l][2m] = cos, [2m+1] = sin (inverse basis, bf16)
// ---------------------------------------------------------------------------
__global__ __launch_bounds__(256) void genTwP(float* __restrict__ TwP) {
  int idx = blockIdx.x * 256 + threadIdx.x;   // l*64 + mg*16 + j ; 131072
  int l = idx >> 6, rem = idx & 63, mg = rem >> 4, j = rem & 15;
  int m = mg * 8 + (j & 7);
  int r = (m * l) & (L_ - 1);
  float ang = (float)r * (6.283185307179586f / (float)L_);
  TwP[idx] = (j < 8) ? cosf(ang) : -sinf(ang);
}

__global__ __launch_bounds__(256) void genTbBf(bf16* __restrict__ Tb) {
  int idx = blockIdx.x * 256 + threadIdx.x;   // l*64 + j ; 131072
  int l = idx >> 6, j = idx & 63;
  int m = j >> 1;
  int r = (m * l) & (L_ - 1);
  float ang = (float)r * (6.283185307179586f / (float)L_);
  float v = (j & 1) ? sinf(ang) : cosf(ang);
  Tb[idx] = __float2bfloat16(v);
}

// ---------------------------------------------------------------------------
// Wf transpose: Wf_{r,i}[i][o][m] fp32 -> Wfm{R,I}[m][io] bf16  (io = i*512+o)
// ---------------------------------------------------------------------------
__global__ __launch_bounds__(256) void twWf(const float* __restrict__ Wfr,
                                            const float* __restrict__ Wfi,
                                            bf16* __restrict__ WfmR,
                                            bf16* __restrict__ WfmI) {
  __shared__ float tile[64][33];
  const size_t io0 = (size_t)blockIdx.x * 64;
#pragma unroll
  for (int arr = 0; arr < 2; arr++) {
    const float* src = arr ? Wfi : Wfr;
    bf16* dst = arr ? WfmI : WfmR;
#pragma unroll
    for (int s = 0; s < 8; s++) {
      int flat = s * 256 + threadIdx.x;
      int r = flat >> 5, m = flat & 31;
      tile[r][m] = src[(io0 + r) * 32 + m];
    }
    __syncthreads();
#pragma unroll
    for (int s = 0; s < 8; s++) {
      int flat = s * 256 + threadIdx.x;
      int m = flat >> 6, io = flat & 63;
      dst[(size_t)m * 262144 + io0 + io] = __float2bfloat16(tile[io][m]);
    }
    __syncthreads();
  }
}

// ---------------------------------------------------------------------------
// bf16 MFMA GEMM (m97 structure): C = post(A @ Wt^T + bias) (+resid)
// 128x128 tile, BK=32, 256 threads (4 waves 2x2), 16x16x32 MFMA.
// Batched via blockIdx.z. MGUARD: valid A rows = M (<128), loads clamped &31.
// EPI: 0 = normal (ldc/coff used), 1 = CC real write, 2 = CC imag write.
// ---------------------------------------------------------------------------
template <bool GELU, bool RESID, bool BIAS, bool OUTBF, bool MGUARD, int EPI>
__global__ __launch_bounds__(256) void gemm_bt(
    const bf16* __restrict__ A, const bf16* __restrict__ Wt,
    const float* __restrict__ bias, const float* __restrict__ resid,
    void* __restrict__ Cout, int M, int N, int K,
    long batchA, long batchB, long batchC, int ldc, int coff) {
  __shared__ __align__(16) bf16 As[128 * 32];
  __shared__ __align__(16) bf16 Bs[128 * 32];
  const int t = threadIdx.x;
  const int lane = t & 63;
  const int wid = t >> 6, wr = wid >> 1, wc = wid & 1;
  const int row0 = blockIdx.x * 128, col0 = blockIdx.y * 128;
  const int zb = blockIdx.z;
  A += (size_t)zb * (size_t)batchA;
  Wt += (size_t)zb * (size_t)batchB;
  const float* residp = nullptr;
  if (RESID) residp = resid + (size_t)zb * (size_t)batchC;

  f32x4 acc[4][4];
#pragma unroll
  for (int i = 0; i < 4; i++)
#pragma unroll
    for (int j = 0; j < 4; j++) acc[i][j] = (f32x4){0.f, 0.f, 0.f, 0.f};

  const int srow = t >> 2, scq = t & 3;      // staging row/chunk
  const int sa0 = MGUARD ? (srow & 31) : srow;
  const int sa1 = MGUARD ? (srow & 31) : (64 + srow);
  bf16* AsW0 = &As[(size_t)(t & ~63) * 8];
  bf16* AsW1 = &As[(size_t)(256 + (t & ~63)) * 8];
  bf16* BsW0 = &Bs[(size_t)(t & ~63) * 8];
  bf16* BsW1 = &Bs[(size_t)(256 + (t & ~63)) * 8];

  for (int k0 = 0; k0 < K; k0 += 32) {
    gl_lds16(A + (size_t)(row0 + sa0) * K + k0 + scq * 8, AsW0);
    gl_lds16(A + (size_t)(row0 + sa1) * K + k0 + scq * 8, AsW1);
    gl_lds16(Wt + (size_t)(col0 + srow) * K + k0 + scq * 8, BsW0);
    gl_lds16(Wt + (size_t)(col0 + 64 + srow) * K + k0 + scq * 8, BsW1);
    __syncthreads();
    bf16x8 af[4], bg[4];
#pragma unroll
    for (int m = 0; m < 4; m++)
      af[m] = *reinterpret_cast<const bf16x8*>(
          &As[(wr * 64 + m * 16 + (lane & 15)) * 32 + (lane >> 4) * 8]);
#pragma unroll
    for (int n = 0; n < 4; n++)
      bg[n] = *reinterpret_cast<const bf16x8*>(
          &Bs[(wc * 64 + n * 16 + (lane & 15)) * 32 + (lane >> 4) * 8]);
#pragma unroll
    for (int m = 0; m < 4; m++)
#pragma unroll
      for (int n = 0; n < 4; n++)
        acc[m][n] = __builtin_amdgcn_mfma_f32_16x16x32_bf16(af[m], bg[n],
                                                            acc[m][n], 0, 0, 0);
    __syncthreads();
  }

  if (EPI != 0) {
    // CC epilogue: CCT[(row*N+col)*64 + 2*zb (+1)] = scale * acc
    const float scale = (EPI == 1) ? ((zb == 0) ? (1.f / (float)L_)
                                                : (2.f / (float)L_))
                                   : (-2.f / (float)L_);
    const int joff = 2 * zb + (EPI == 2 ? 1 : 0);
    bf16* Cb = (bf16*)Cout;
#pragma unroll
    for (int n = 0; n < 4; n++) {
      int col = col0 + wc * 64 + n * 16 + (lane & 15);
#pragma unroll
      for (int m = 0; m < 4; m++) {
#pragma unroll
        for (int j = 0; j < 4; j++) {
          int row = row0 + wr * 64 + m * 16 + (lane >> 4) * 4 + j;
          if (row < M)
            Cb[((size_t)row * N + col) * 64 + joff] =
                __float2bfloat16(acc[m][n][j] * scale);
        }
      }
    }
    return;
  }

  float* Cf = (float*)Cout;
  bf16* Cb = (bf16*)Cout;
  const size_t cbase = (size_t)zb * (size_t)batchC;
#pragma unroll
  for (int n = 0; n < 4; n++) {
    int col = col0 + wc * 64 + n * 16 + (lane & 15);
    float bs = 0.f;
    if (BIAS) bs = bias[col];
#pragma unroll
    for (int m = 0; m < 4; m++) {
#pragma unroll
      for (int j = 0; j < 4; j++) {
        int row = row0 + wr * 64 + m * 16 + (lane >> 4) * 4 + j;
        if (MGUARD && row >= M) continue;
        float v = acc[m][n][j] + bs;
        if (GELU) v = 0.5f * v * (1.0f + erff(v * 0.70710678118654752f));
        if (RESID) v += residp[(size_t)row * N + col];
        size_t idx = cbase + (size_t)row * ldc + coff + col;
        if (OUTBF) Cb[idx] = __float2bfloat16(v);
        else Cf[idx] = v;
      }
    }
  }
}

// ---------------------------------------------------------------------------
// Stage B: forward DFT on 32 kept modes, partial over l-chunks of 256.
// grid (b=32, ig=8, lc=8); per-wave twiddle slice staged via global_load_lds.
// ---------------------------------------------------------------------------
__global__ __launch_bounds__(256) void stageB(
    const bf16* __restrict__ q, const float* __restrict__ TwP,
    float* __restrict__ XFp_r, float* __restrict__ XFp_i) {
  __shared__ __align__(16) float Tls[4 * 128 * 16];   // 32 KB
  const int b = blockIdx.x, ig = blockIdx.y, lc = blockIdx.z;
  const int t = threadIdx.x, lane = t & 63, mg = t >> 6;
  const int i0 = ig * 64;
  float ar[8], ai[8];
#pragma unroll
  for (int k = 0; k < 8; k++) { ar[k] = 0.f; ai[k] = 0.f; }
  float* TlsW = &Tls[mg * 2048];

  for (int h = 0; h < 2; h++) {
    const int hb = lc * 256 + h * 128;
#pragma unroll
    for (int s = 0; s < 8; s++) {
      int flat = s * 64 + lane;            // 0..511
      int l = flat >> 2, q4 = flat & 3;
      gl_lds16(TwP + ((size_t)(hb + l) * 4 + mg) * 16 + q4 * 4,
               TlsW + s * 256);
    }
    __syncthreads();
#pragma unroll 4
    for (int l = 0; l < 128; l++) {
      float qv = __bfloat162float(q[((size_t)b * L_ + hb + l) * D_ + i0 + lane]);
      const float* Tp = TlsW + l * 16;
      float4 c0 = *(const float4*)(Tp);
      float4 c1 = *(const float4*)(Tp + 4);
      float4 s0 = *(const float4*)(Tp + 8);
      float4 s1 = *(const float4*)(Tp + 12);
      ar[0] += qv * c0.x; ar[1] += qv * c0.y; ar[2] += qv * c0.z; ar[3] += qv * c0.w;
      ar[4] += qv * c1.x; ar[5] += qv * c1.y; ar[6] += qv * c1.z; ar[7] += qv * c1.w;
      ai[0] += qv * s0.x; ai[1] += qv * s0.y; ai[2] += qv * s0.z; ai[3] += qv * s0.w;
      ai[4] += qv * s1.x; ai[5] += qv * s1.y; ai[6] += qv * s1.z; ai[7] += qv * s1.w;
    }
    __syncthreads();
  }
  size_t base = (((size_t)lc * B_ + b) * D_ + i0 + lane) * 32 + mg * 8;
  float4 r0 = {ar[0], ar[1], ar[2], ar[3]}, r1 = {ar[4], ar[5], ar[6], ar[7]};
  float4 i0v = {ai[0], ai[1], ai[2], ai[3]}, i1v = {ai[4], ai[5], ai[6], ai[7]};
  *(float4*)(XFp_r + base) = r0;
  *(float4*)(XFp_r + base + 4) = r1;
  *(float4*)(XFp_i + base) = i0v;
  *(float4*)(XFp_i + base + 4) = i1v;
}

// ---------------------------------------------------------------------------
// Reduce partials and emit packed bf16 A-operands for the CC GEMMs:
//   Aneg[m][b][k]:  k<512 -> XFr[b][k],  k>=512 -> -XFi[b][k-512]
//   Aswap[m][b][k]: k<512 -> XFi[b][k],  k>=512 ->  XFr[b][k-512]
// grid (b=32, ic=8): 64 i x 32 m per block.
// ---------------------------------------------------------------------------
__global__ __launch_bounds__(256) void reduceXFT(
    const float* __restrict__ XFp_r, const float* __restrict__ XFp_i,
    bf16* __restrict__ Aneg, bf16* __restrict__ Aswap) {
  __shared__ float smr[64][33], smi[64][33];
  const int b = blockIdx.x, ic = blockIdx.y;
  const int i0 = ic * 64;
  const size_t CS = (size_t)B_ * D_ * 32;
#pragma unroll
  for (int s = 0; s < 8; s++) {
    int flat = s * 256 + threadIdx.x;       // 2048 = 64 i x 32 m
    int i = flat >> 5, m = flat & 31;
    size_t e = ((size_t)b * D_ + i0 + i) * 32 + m;
    float sr = 0.f, si = 0.f;
#pragma unroll
    for (int c = 0; c < 8; c++) { sr += XFp_r[c * CS + e]; si += XFp_i[c * CS + e]; }
    smr[i][m] = sr;
    smi[i][m] = si;
  }
  __syncthreads();
#pragma unroll
  for (int s = 0; s < 8; s++) {
    int flat = s * 256 + threadIdx.x;
    int m = flat >> 6, i = flat & 63;
    float sr = smr[i][m], si = smi[i][m];
    size_t base = ((size_t)m * B_ + b) * 1024;
    Aneg[base + i0 + i] = __float2bfloat16(sr);
    Aneg[base + 512 + i0 + i] = __float2bfloat16(-si);
    Aswap[base + i0 + i] = __float2bfloat16(si);
    Aswap[base + 512 + i0 + i] = __float2bfloat16(sr);
  }
}

// ---------------------------------------------------------------------------
// Stage E: series decomposition residual (rolling window, replicate pad 64/63)
// ---------------------------------------------------------------------------
__global__ __launch_bounds__(256) void stageE(const float* __restrict__ in,
                                              float* __restrict__ out) {
  const int b = blockIdx.x, dg = blockIdx.y, lc = blockIdx.z;
  const int d = dg * 256 + threadIdx.x;
  const float* col = in + (size_t)b * L_ * D_ + d;
  float* ocol = out + (size_t)b * L_ * D_ + d;
  const int l0 = lc * 256;
  float Wsum = 0.f;
  for (int s = l0 - 64; s < l0 + 64; s++) {
    int cl = min(max(s, 0), L_ - 1);
    Wsum += col[(size_t)cl * D_];
  }
  for (int l = l0; l < l0 + 256; l++) {
    float v = col[(size_t)l * D_];
    ocol[(size_t)l * D_] = v - Wsum * (1.f / 128.f);
    int fa = min(l + 64, L_ - 1);
    int fb = max(l - 64, 0);
    Wsum += col[(size_t)fa * D_] - col[(size_t)fb * D_];
  }
}

// ---------------------------------------------------------------------------
// BatchNorm over (b, d) per time step l.
// ---------------------------------------------------------------------------
__global__ __launch_bounds__(256) void bnStats(const float* __restrict__ res,
                                               float* __restrict__ meanb,
                                               float* __restrict__ rstdb) {
  const int l = blockIdx.x;
  const int t = threadIdx.x;
  float s = 0.f, s2 = 0.f;
  for (int b = 0; b < B_; b++) {
    const float* p = res + ((size_t)b * L_ + l) * D_;
    for (int d = t; d < D_; d += 256) {
      float v = p[d];
      s += v;
      s2 += v * v;
    }
  }
#pragma unroll
  for (int off = 32; off > 0; off >>= 1) {
    s += __shfl_down(s, off, 64);
    s2 += __shfl_down(s2, off, 64);
  }
  __shared__ float shs[4], shs2[4];
  int wid = t >> 6;
  if ((t & 63) == 0) { shs[wid] = s; shs2[wid] = s2; }
  __syncthreads();
  if (t == 0) {
    float S = shs[0] + shs[1] + shs[2] + shs[3];
    float S2 = shs2[0] + shs2[1] + shs2[2] + shs2[3];
    const float inv = 1.f / (float)(B_ * D_);
    float mean = S * inv;
    float var = S2 * inv - mean * mean;
    meanb[l] = mean;
    rstdb[l] = rsqrtf(var + 1e-5f);
  }
}

__global__ __launch_bounds__(256) void bnApply(
    const float* __restrict__ res, const float* __restrict__ gamma,
    const float* __restrict__ beta, const float* __restrict__ meanb,
    const float* __restrict__ rstdb, float* __restrict__ out) {
  size_t idx = (size_t)blockIdx.x * 256 + threadIdx.x;   // float4 index
  if (idx >= NBIG / 4) return;
  size_t e = idx * 4;
  int l = (int)((e >> 9) & (L_ - 1));
  float4 v = *(const float4*)(res + e);
  float m = meanb[l], rs = rstdb[l];
  float g = gamma[l] * rs, bt = beta[l];
  float4 o;
  o.x = (v.x - m) * g + bt;
  o.y = (v.y - m) * g + bt;
  o.z = (v.z - m) * g + bt;
  o.w = (v.w - m) * g + bt;
  *(float4*)(out + e) = o;
}

// ---------------------------------------------------------------------------
extern "C" void kernel_launch(void* const* d_in, const int* in_sizes, int n_in,
                              void* d_out, int out_size, void* d_ws,
                              size_t ws_size, hipStream_t stream) {
  const float* x      = (const float*)d_in[0];
  const float* W_in   = (const float*)d_in[1];
  const float* b_in   = (const float*)d_in[2];
  const float* Wf_r   = (const float*)d_in[3];
  const float* Wf_i   = (const float*)d_in[4];
  const float* W_out  = (const float*)d_in[5];
  const float* b_out  = (const float*)d_in[6];
  const float* W_c1   = (const float*)d_in[7];
  const float* W_c2   = (const float*)d_in[8];
  const float* gamma  = (const float*)d_in[9];
  const float* beta   = (const float*)d_in[10];
  float* outp = (float*)d_out;

  // ---- workspace layout ----
  float* f = (float*)d_ws;
  float* buf0 = f;                                   // NBIG fp32 (xr -> res)
  // aliases inside buf0 (all dead before stageE writes xr):
  float* XFp_r = buf0;                               // 8*524288 f
  float* XFp_i = XFp_r + (size_t)8 * 524288;         // 8*524288 f
  bf16*  WfmR  = (bf16*)(XFp_i + (size_t)8 * 524288);// 8388608 bf16
  bf16*  WfmI  = WfmR + (size_t)8388608;             // 8388608 bf16
  bf16*  Woutbf= WfmI + (size_t)8388608;             // 262144 bf16
  bf16*  Wcat  = Woutbf + 262144;                    // 32*512*1024 bf16
  bf16*  Aneg  = Wcat + (size_t)32 * 512 * 1024;     // 1048576 bf16
  bf16*  Aswap = Aneg + 1048576;                     // 1048576 bf16
  bf16*  CCT   = Aswap + 1048576;                    // 32*512*64 bf16
  // tail after buf0:
  float* TwP   = f + NBIG;                           // 131072 f
  bf16*  Tbbf  = (bf16*)(TwP + 131072);              // 131072 bf16
  bf16*  Wibf  = Tbbf + 131072;                      // 262144 bf16 x3
  bf16*  W1bf  = Wibf + 262144;
  bf16*  W2bf  = W1bf + 262144;
  float* meanb = (float*)(W2bf + 262144);
  float* rstdb = meanb + L_;

  // d_out double-duty: [xbf | qbf], later xr_raw fp32, later [y1bf | xrbf]
  bf16* xbf  = (bf16*)d_out;
  bf16* qbf  = xbf + NBIG;
  bf16* y1bf = (bf16*)d_out;
  bf16* xrbf = ((bf16*)d_out) + NBIG;

  // tables + dtype conversions
  genTwP<<<512, 256, 0, stream>>>(TwP);
  genTbBf<<<512, 256, 0, stream>>>(Tbbf);
  f2bfK<<<2048, 256, 0, stream>>>((const float4*)x, (ushort4*)xbf, NBIG / 4);
  f2bfK<<<256, 256, 0, stream>>>((const float4*)W_in, (ushort4*)Wibf, 65536);
  f2bfK<<<256, 256, 0, stream>>>((const float4*)W_c1, (ushort4*)W1bf, 65536);
  f2bfK<<<256, 256, 0, stream>>>((const float4*)W_c2, (ushort4*)W2bf, 65536);
  f2bfK<<<256, 256, 0, stream>>>((const float4*)W_out, (ushort4*)Woutbf, 65536);
  twWf<<<4096, 256, 0, stream>>>(Wf_r, Wf_i, WfmR, WfmI);

  // fold W_out into Wf: Wcat[m][d][0:512] = sum_o Wout[d][o]*Wf_r[i][o][m]
  //                     Wcat[m][d][512:1024] = ... Wf_i ...
  gemm_bt<false, false, false, true, false, 0><<<dim3(4, 4, 32), 256, 0, stream>>>(
      Woutbf, WfmR, nullptr, nullptr, Wcat, 512, 512, 512,
      0, 262144, 524288, 1024, 0);
  gemm_bt<false, false, false, true, false, 0><<<dim3(4, 4, 32), 256, 0, stream>>>(
      Woutbf, WfmI, nullptr, nullptr, Wcat, 512, 512, 512,
      0, 262144, 524288, 1024, 512);

  // A: q = x @ W_in^T + b_in  (bf16 out)
  gemm_bt<false, false, true, true, false, 0><<<dim3(512, 4, 1), 256, 0, stream>>>(
      xbf, Wibf, b_in, nullptr, qbf, BLROWS, D_, D_, 0, 0, 0, D_, 0);

  // B: forward DFT partials + reduce/pack
  stageB<<<dim3(B_, 8, 8), 256, 0, stream>>>(qbf, TwP, XFp_r, XFp_i);
  reduceXFT<<<dim3(B_, 8), 256, 0, stream>>>(XFp_r, XFp_i, Aneg, Aswap);

  // CC GEMMs: Re(G) and Im(G) -> scaled CCT[b][d][64]
  gemm_bt<false, false, false, false, true, 1><<<dim3(1, 4, 32), 256, 0, stream>>>(
      Aneg, Wcat, nullptr, nullptr, CCT, 32, 512, 1024,
      32768, 524288, 0, 0, 0);
  gemm_bt<false, false, false, false, true, 2><<<dim3(1, 4, 32), 256, 0, stream>>>(
      Aswap, Wcat, nullptr, nullptr, CCT, 32, 512, 1024,
      32768, 524288, 0, 0, 0);

  // D: xr_raw = x + b_out + Tb @ CCT^T   (batched MFMA, fp32 -> d_out)
  gemm_bt<false, true, true, false, false, 0><<<dim3(16, 4, 32), 256, 0, stream>>>(
      Tbbf, CCT, b_out, x, outp, L_, D_, 64, 0, (long)D_ * 64,
      (long)L_ * D_, D_, 0);

  // E: xr = xr_raw - movavg(xr_raw) -> buf0 fp32
  stageE<<<dim3(B_, 2, 8), 256, 0, stream>>>(outp, buf0);
  // bf16 copy of xr (separate pass: d_out fp32 is dead by now, no overlap race)
  f2bfK<<<2048, 256, 0, stream>>>((const float4*)buf0, (ushort4*)xrbf, NBIG / 4);

  // F1: y1 = gelu(xr @ Wc1^T)  (bf16 out)
  gemm_bt<true, false, false, true, false, 0><<<dim3(512, 4, 1), 256, 0, stream>>>(
      xrbf, W1bf, nullptr, nullptr, y1bf, BLROWS, D_, D_, 0, 0, 0, D_, 0);

  // F2: res = xr + y1 @ Wc2^T  (fp32, in-place on buf0)
  gemm_bt<false, true, false, false, false, 0><<<dim3(512, 4, 1), 256, 0, stream>>>(
      y1bf, W2bf, nullptr, buf0, buf0, BLROWS, D_, D_, 0, 0, 0, D_, 0);

  // G: BatchNorm over (b, d) per l
  bnStats<<<L_, 256, 0, stream>>>(buf0, meanb, rstdb);
  bnApply<<<(NBIG / 4 + 255) / 256, 256, 0, stream>>>(buf0, gamma, beta, meanb,
                                                      rstdb, outp);
}

// Round 5
// 739.184 us; speedup vs baseline: 3.6357x; 1.1326x over previous
//
#include <hip/hip_runtime.h>
#include <hip/hip_bf16.h>
#include <math.h>

#define B_   32
#define L_   2048
#define D_   512
#define BLROWS (B_*L_)                 // 65536
#define NBIG ((size_t)BLROWS * D_)     // 33554432

typedef __hip_bfloat16 bf16;
using bf16x8 = __attribute__((ext_vector_type(8))) short;
using f32x4  = __attribute__((ext_vector_type(4))) float;

__device__ __forceinline__ unsigned short f2b(float f) {
  bf16 h = __float2bfloat16(f);
  return *reinterpret_cast<unsigned short*>(&h);
}

__device__ __forceinline__ void gl_lds16(const void* g, void* l) {
  __builtin_amdgcn_global_load_lds(
      (const __attribute__((address_space(1))) void*)g,
      (__attribute__((address_space(3))) void*)l, 16, 0, 0);
}

// ---------------------------------------------------------------------------
// fp32 -> bf16 vectorized converter
// ---------------------------------------------------------------------------
__global__ __launch_bounds__(256) void f2bfK(const float4* __restrict__ src,
                                             ushort4* __restrict__ dst,
                                             size_t n4) {
  for (size_t i = (size_t)blockIdx.x * 256 + threadIdx.x; i < n4;
       i += (size_t)gridDim.x * 256) {
    float4 v = src[i];
    ushort4 o;
    o.x = f2b(v.x); o.y = f2b(v.y); o.z = f2b(v.z); o.w = f2b(v.w);
    dst[i] = o;
  }
}

// ---------------------------------------------------------------------------
// Twiddle tables.
// TwP[l][mg][j]: j<8 -> cos(2pi*m*l/L), j>=8 -> -sin(...), m = mg*8 + (j&7)
// TbF[l][2m]=cos, [2m+1]=sin (fp32 inverse basis)
// TbD = TbF - movavg_l(TbF)  (replicate-pad window 128: [l-64, l+63])
// ---------------------------------------------------------------------------
__global__ __launch_bounds__(256) void genTwP(float* __restrict__ TwP) {
  int idx = blockIdx.x * 256 + threadIdx.x;   // l*64 + mg*16 + j ; 131072
  int l = idx >> 6, rem = idx & 63, mg = rem >> 4, j = rem & 15;
  int m = mg * 8 + (j & 7);
  int r = (m * l) & (L_ - 1);
  float ang = (float)r * (6.283185307179586f / (float)L_);
  TwP[idx] = (j < 8) ? cosf(ang) : -sinf(ang);
}

__global__ __launch_bounds__(256) void genTbF(float* __restrict__ Tb) {
  int idx = blockIdx.x * 256 + threadIdx.x;   // l*64 + j ; 131072
  int l = idx >> 6, j = idx & 63;
  int m = j >> 1;
  int r = (m * l) & (L_ - 1);
  float ang = (float)r * (6.283185307179586f / (float)L_);
  Tb[idx] = (j & 1) ? sinf(ang) : cosf(ang);
}

__global__ __launch_bounds__(256) void genTbD(const float* __restrict__ Tb,
                                              float* __restrict__ TbD) {
  int idx = blockIdx.x * 256 + threadIdx.x;   // l*64 + j ; 131072
  int l = idx >> 6, j = idx & 63;
  float s = 0.f;
  for (int t = l - 64; t < l + 64; t++) {
    int cl = min(max(t, 0), L_ - 1);
    s += Tb[cl * 64 + j];
  }
  TbD[idx] = Tb[idx] - s * (1.f / 128.f);
}

// ---------------------------------------------------------------------------
// Wf transpose: Wf_{r,i}[i][o][m] fp32 -> Wfm{R,I}[m][io] bf16  (io = i*512+o)
// ---------------------------------------------------------------------------
__global__ __launch_bounds__(256) void twWf(const float* __restrict__ Wfr,
                                            const float* __restrict__ Wfi,
                                            bf16* __restrict__ WfmR,
                                            bf16* __restrict__ WfmI) {
  __shared__ float tile[64][33];
  const size_t io0 = (size_t)blockIdx.x * 64;
#pragma unroll
  for (int arr = 0; arr < 2; arr++) {
    const float* src = arr ? Wfi : Wfr;
    bf16* dst = arr ? WfmI : WfmR;
#pragma unroll
    for (int s = 0; s < 8; s++) {
      int flat = s * 256 + threadIdx.x;
      int r = flat >> 5, m = flat & 31;
      tile[r][m] = src[(io0 + r) * 32 + m];
    }
    __syncthreads();
#pragma unroll
    for (int s = 0; s < 8; s++) {
      int flat = s * 256 + threadIdx.x;
      int m = flat >> 6, io = flat & 63;
      dst[(size_t)m * 262144 + io0 + io] = __float2bfloat16(tile[io][m]);
    }
    __syncthreads();
  }
}

// ---------------------------------------------------------------------------
// bf16 MFMA GEMM, double-buffered LDS (T3-minimum): one barrier per K-step,
// next tile's global_load_lds in flight during current MFMA.
// 128x128 tile, BK=32, 256 threads (4 waves 2x2), 16x16x32 MFMA.
// EPI: 0 = normal (ldc/coff), 1 = CCd real write (fp32), 2 = CCd imag write.
// RESBF: residual input read as bf16.
// ---------------------------------------------------------------------------
template <bool GELU, bool RESID, bool BIAS, bool OUTBF, bool MGUARD, int EPI,
          bool RESBF>
__global__ __launch_bounds__(256) void gemm_bt(
    const bf16* __restrict__ A, const bf16* __restrict__ Wt,
    const float* __restrict__ bias, const float* __restrict__ resid,
    void* __restrict__ Cout, int M, int N, int K,
    long batchA, long batchB, long batchC, int ldc, int coff) {
  __shared__ __align__(16) bf16 As[2][128 * 32];
  __shared__ __align__(16) bf16 Bs[2][128 * 32];
  const int t = threadIdx.x;
  const int lane = t & 63;
  const int wid = t >> 6, wr = wid >> 1, wc = wid & 1;
  const int row0 = blockIdx.x * 128, col0 = blockIdx.y * 128;
  const int zb = blockIdx.z;
  A += (size_t)zb * (size_t)batchA;
  Wt += (size_t)zb * (size_t)batchB;

  f32x4 acc[4][4];
#pragma unroll
  for (int i = 0; i < 4; i++)
#pragma unroll
    for (int j = 0; j < 4; j++) acc[i][j] = (f32x4){0.f, 0.f, 0.f, 0.f};

  const int srow = t >> 2, scq = t & 3;      // staging row/chunk
  const int sa0 = MGUARD ? (srow & 31) : srow;
  const int sa1 = MGUARD ? (srow & 31) : (64 + srow);
  const int wbase = (t & ~63) * 8;

  auto stage = [&](int buf, int k0) {
    gl_lds16(A + (size_t)(row0 + sa0) * K + k0 + scq * 8, &As[buf][wbase]);
    gl_lds16(A + (size_t)(row0 + sa1) * K + k0 + scq * 8,
             &As[buf][2048 + wbase]);
    gl_lds16(Wt + (size_t)(col0 + srow) * K + k0 + scq * 8, &Bs[buf][wbase]);
    gl_lds16(Wt + (size_t)(col0 + 64 + srow) * K + k0 + scq * 8,
             &Bs[buf][2048 + wbase]);
  };

  stage(0, 0);
  int cur = 0;
  for (int k0 = 0; k0 < K; k0 += 32) {
    __syncthreads();                    // stage(cur) drained; prev reads done
    if (k0 + 32 < K) stage(cur ^ 1, k0 + 32);
    bf16x8 af[4], bg[4];
#pragma unroll
    for (int m = 0; m < 4; m++)
      af[m] = *reinterpret_cast<const bf16x8*>(
          &As[cur][(wr * 64 + m * 16 + (lane & 15)) * 32 + (lane >> 4) * 8]);
#pragma unroll
    for (int n = 0; n < 4; n++)
      bg[n] = *reinterpret_cast<const bf16x8*>(
          &Bs[cur][(wc * 64 + n * 16 + (lane & 15)) * 32 + (lane >> 4) * 8]);
#pragma unroll
    for (int m = 0; m < 4; m++)
#pragma unroll
      for (int n = 0; n < 4; n++)
        acc[m][n] = __builtin_amdgcn_mfma_f32_16x16x32_bf16(af[m], bg[n],
                                                            acc[m][n], 0, 0, 0);
    cur ^= 1;
  }

  if (EPI != 0) {
    // CCd epilogue: CCd[(row*64 + joff)*512 + col] = scale * acc (fp32)
    const float scale = (EPI == 1) ? ((zb == 0) ? (1.f / (float)L_)
                                                : (2.f / (float)L_))
                                   : (-2.f / (float)L_);
    const int joff = 2 * zb + (EPI == 2 ? 1 : 0);
    float* Cf = (float*)Cout;
#pragma unroll
    for (int n = 0; n < 4; n++) {
      int col = col0 + wc * 64 + n * 16 + (lane & 15);
#pragma unroll
      for (int m = 0; m < 4; m++) {
#pragma unroll
        for (int j = 0; j < 4; j++) {
          int row = row0 + wr * 64 + m * 16 + (lane >> 4) * 4 + j;
          if (row < M)
            Cf[((size_t)row * 64 + joff) * 512 + col] = acc[m][n][j] * scale;
        }
      }
    }
    return;
  }

  const float* residp = nullptr;
  if (RESID) residp = resid + (size_t)zb * (size_t)batchC;
  float* Cf = (float*)Cout;
  bf16* Cb = (bf16*)Cout;
  const size_t cbase = (size_t)zb * (size_t)batchC;
#pragma unroll
  for (int n = 0; n < 4; n++) {
    int col = col0 + wc * 64 + n * 16 + (lane & 15);
    float bs = 0.f;
    if (BIAS) bs = bias[col];
#pragma unroll
    for (int m = 0; m < 4; m++) {
#pragma unroll
      for (int j = 0; j < 4; j++) {
        int row = row0 + wr * 64 + m * 16 + (lane >> 4) * 4 + j;
        if (MGUARD && row >= M) continue;
        float v = acc[m][n][j] + bs;
        if (GELU) v = 0.5f * v * (1.0f + erff(v * 0.70710678118654752f));
        if (RESID) {
          float rv = RESBF
              ? __bfloat162float(
                    ((const bf16*)residp)[(size_t)row * N + col])
              : residp[(size_t)row * N + col];
          v += rv;
        }
        size_t idx = cbase + (size_t)row * ldc + coff + col;
        if (OUTBF) Cb[idx] = __float2bfloat16(v);
        else Cf[idx] = v;
      }
    }
  }
}

// ---------------------------------------------------------------------------
// Stage B: forward DFT on 32 kept modes, partial over l-chunks of 256.
// grid (b=32, ig=8, lc=8); per-wave twiddle slice staged via global_load_lds.
// ---------------------------------------------------------------------------
__global__ __launch_bounds__(256) void stageB(
    const bf16* __restrict__ q, const float* __restrict__ TwP,
    float* __restrict__ XFp_r, float* __restrict__ XFp_i) {
  __shared__ __align__(16) float Tls[4 * 128 * 16];   // 32 KB
  const int b = blockIdx.x, ig = blockIdx.y, lc = blockIdx.z;
  const int t = threadIdx.x, lane = t & 63, mg = t >> 6;
  const int i0 = ig * 64;
  float ar[8], ai[8];
#pragma unroll
  for (int k = 0; k < 8; k++) { ar[k] = 0.f; ai[k] = 0.f; }
  float* TlsW = &Tls[mg * 2048];

  for (int h = 0; h < 2; h++) {
    const int hb = lc * 256 + h * 128;
#pragma unroll
    for (int s = 0; s < 8; s++) {
      int flat = s * 64 + lane;            // 0..511
      int l = flat >> 2, q4 = flat & 3;
      gl_lds16(TwP + ((size_t)(hb + l) * 4 + mg) * 16 + q4 * 4,
               TlsW + s * 256);
    }
    __syncthreads();
#pragma unroll 4
    for (int l = 0; l < 128; l++) {
      float qv = __bfloat162float(q[((size_t)b * L_ + hb + l) * D_ + i0 + lane]);
      const float* Tp = TlsW + l * 16;
      float4 c0 = *(const float4*)(Tp);
      float4 c1 = *(const float4*)(Tp + 4);
      float4 s0 = *(const float4*)(Tp + 8);
      float4 s1 = *(const float4*)(Tp + 12);
      ar[0] += qv * c0.x; ar[1] += qv * c0.y; ar[2] += qv * c0.z; ar[3] += qv * c0.w;
      ar[4] += qv * c1.x; ar[5] += qv * c1.y; ar[6] += qv * c1.z; ar[7] += qv * c1.w;
      ai[0] += qv * s0.x; ai[1] += qv * s0.y; ai[2] += qv * s0.z; ai[3] += qv * s0.w;
      ai[4] += qv * s1.x; ai[5] += qv * s1.y; ai[6] += qv * s1.z; ai[7] += qv * s1.w;
    }
    __syncthreads();
  }
  size_t base = (((size_t)lc * B_ + b) * D_ + i0 + lane) * 32 + mg * 8;
  float4 r0 = {ar[0], ar[1], ar[2], ar[3]}, r1 = {ar[4], ar[5], ar[6], ar[7]};
  float4 i0v = {ai[0], ai[1], ai[2], ai[3]}, i1v = {ai[4], ai[5], ai[6], ai[7]};
  *(float4*)(XFp_r + base) = r0;
  *(float4*)(XFp_r + base + 4) = r1;
  *(float4*)(XFp_i + base) = i0v;
  *(float4*)(XFp_i + base + 4) = i1v;
}

// ---------------------------------------------------------------------------
// Reduce partials and emit packed bf16 A-operands for the CC GEMMs.
// ---------------------------------------------------------------------------
__global__ __launch_bounds__(256) void reduceXFT(
    const float* __restrict__ XFp_r, const float* __restrict__ XFp_i,
    bf16* __restrict__ Aneg, bf16* __restrict__ Aswap) {
  __shared__ float smr[64][33], smi[64][33];
  const int b = blockIdx.x, ic = blockIdx.y;
  const int i0 = ic * 64;
  const size_t CS = (size_t)B_ * D_ * 32;
#pragma unroll
  for (int s = 0; s < 8; s++) {
    int flat = s * 256 + threadIdx.x;       // 2048 = 64 i x 32 m
    int i = flat >> 5, m = flat & 31;
    size_t e = ((size_t)b * D_ + i0 + i) * 32 + m;
    float sr = 0.f, si = 0.f;
#pragma unroll
    for (int c = 0; c < 8; c++) { sr += XFp_r[c * CS + e]; si += XFp_i[c * CS + e]; }
    smr[i][m] = sr;
    smi[i][m] = si;
  }
  __syncthreads();
#pragma unroll
  for (int s = 0; s < 8; s++) {
    int flat = s * 256 + threadIdx.x;
    int m = flat >> 6, i = flat & 63;
    float sr = smr[i][m], si = smi[i][m];
    size_t base = ((size_t)m * B_ + b) * 1024;
    Aneg[base + i0 + i] = __float2bfloat16(sr);
    Aneg[base + 512 + i0 + i] = __float2bfloat16(-si);
    Aswap[base + i0 + i] = __float2bfloat16(si);
    Aswap[base + 512 + i0 + i] = __float2bfloat16(sr);
  }
}

// ---------------------------------------------------------------------------
// Stage DE (fused): xr = (x - MA(x)) + sum_j TbD[l][j]*CCd[b][j][d], bf16 out.
// b_out cancels (constant along l under replicate-pad moving average).
// grid (b=32, lc=16), 512 threads (one d each). CC row kept in 64 registers,
// TbD tile (128x64 fp32, 32 KB) in LDS (broadcast reads, conflict-free).
// ---------------------------------------------------------------------------
__global__ __launch_bounds__(512, 2) void stageDE(
    const float* __restrict__ x, const float* __restrict__ TbD,
    const float* __restrict__ CCd, bf16* __restrict__ xrbf) {
  __shared__ float Ts[128][64];
  const int b = blockIdx.x, lc = blockIdx.y;
  const int d = threadIdx.x;
  const int l0 = lc * 128;
#pragma unroll
  for (int s = 0; s < 16; s++) {
    int flat = s * 512 + d;           // 0..8191
    int r = flat >> 6, j = flat & 63;
    Ts[r][j] = TbD[(size_t)(l0 + r) * 64 + j];
  }
  float cc[64];
#pragma unroll
  for (int j = 0; j < 64; j++) cc[j] = CCd[((size_t)b * 64 + j) * 512 + d];
  __syncthreads();

  const float* col = x + (size_t)b * L_ * D_ + d;
  bf16* ocol = xrbf + (size_t)b * L_ * D_ + d;
  float Wsum = 0.f;
  for (int s = l0 - 64; s < l0 + 64; s++) {
    int cl = min(max(s, 0), L_ - 1);
    Wsum += col[(size_t)cl * D_];
  }
  for (int l = l0; l < l0 + 128; l++) {
    float v = col[(size_t)l * D_];
    float mix = 0.f;
#pragma unroll
    for (int j = 0; j < 64; j++) mix += Ts[l - l0][j] * cc[j];
    float r = v - Wsum * (1.f / 128.f) + mix;
    ocol[(size_t)l * D_] = __float2bfloat16(r);
    int fa = min(l + 64, L_ - 1);
    int fb = max(l - 64, 0);
    Wsum += col[(size_t)fa * D_] - col[(size_t)fb * D_];
  }
}

// ---------------------------------------------------------------------------
// BatchNorm over (b, d) per time step l.
// ---------------------------------------------------------------------------
__global__ __launch_bounds__(256) void bnStats(const float* __restrict__ res,
                                               float* __restrict__ meanb,
                                               float* __restrict__ rstdb) {
  const int l = blockIdx.x;
  const int t = threadIdx.x;
  float s = 0.f, s2 = 0.f;
  for (int b = 0; b < B_; b++) {
    const float* p = res + ((size_t)b * L_ + l) * D_;
    for (int d = t; d < D_; d += 256) {
      float v = p[d];
      s += v;
      s2 += v * v;
    }
  }
#pragma unroll
  for (int off = 32; off > 0; off >>= 1) {
    s += __shfl_down(s, off, 64);
    s2 += __shfl_down(s2, off, 64);
  }
  __shared__ float shs[4], shs2[4];
  int wid = t >> 6;
  if ((t & 63) == 0) { shs[wid] = s; shs2[wid] = s2; }
  __syncthreads();
  if (t == 0) {
    float S = shs[0] + shs[1] + shs[2] + shs[3];
    float S2 = shs2[0] + shs2[1] + shs2[2] + shs2[3];
    const float inv = 1.f / (float)(B_ * D_);
    float mean = S * inv;
    float var = S2 * inv - mean * mean;
    meanb[l] = mean;
    rstdb[l] = rsqrtf(var + 1e-5f);
  }
}

__global__ __launch_bounds__(256) void bnApply(
    const float* __restrict__ res, const float* __restrict__ gamma,
    const float* __restrict__ beta, const float* __restrict__ meanb,
    const float* __restrict__ rstdb, float* __restrict__ out) {
  size_t idx = (size_t)blockIdx.x * 256 + threadIdx.x;   // float4 index
  if (idx >= NBIG / 4) return;
  size_t e = idx * 4;
  int l = (int)((e >> 9) & (L_ - 1));
  float4 v = *(const float4*)(res + e);
  float m = meanb[l], rs = rstdb[l];
  float g = gamma[l] * rs, bt = beta[l];
  float4 o;
  o.x = (v.x - m) * g + bt;
  o.y = (v.y - m) * g + bt;
  o.z = (v.z - m) * g + bt;
  o.w = (v.w - m) * g + bt;
  *(float4*)(out + e) = o;
}

// ---------------------------------------------------------------------------
extern "C" void kernel_launch(void* const* d_in, const int* in_sizes, int n_in,
                              void* d_out, int out_size, void* d_ws,
                              size_t ws_size, hipStream_t stream) {
  const float* x      = (const float*)d_in[0];
  const float* W_in   = (const float*)d_in[1];
  const float* b_in   = (const float*)d_in[2];
  const float* Wf_r   = (const float*)d_in[3];
  const float* Wf_i   = (const float*)d_in[4];
  const float* W_out  = (const float*)d_in[5];
  const float* b_out  = (const float*)d_in[6];  // cancels in decomposition
  const float* W_c1   = (const float*)d_in[7];
  const float* W_c2   = (const float*)d_in[8];
  const float* gamma  = (const float*)d_in[9];
  const float* beta   = (const float*)d_in[10];
  float* outp = (float*)d_out;
  (void)b_out;

  // ---- workspace layout ----
  float* f = (float*)d_ws;
  float* buf0 = f;                                   // NBIG fp32 (res)
  // aliases inside buf0 (all dead before F2 writes res):
  float* XFp_r = buf0;                               // 8*524288 f
  float* XFp_i = XFp_r + (size_t)8 * 524288;         // 8*524288 f
  bf16*  WfmR  = (bf16*)(XFp_i + (size_t)8 * 524288);// 8388608 bf16
  bf16*  WfmI  = WfmR + (size_t)8388608;             // 8388608 bf16
  bf16*  Woutbf= WfmI + (size_t)8388608;             // 262144 bf16
  bf16*  Wcat  = Woutbf + 262144;                    // 32*512*1024 bf16
  bf16*  Aneg  = Wcat + (size_t)32 * 512 * 1024;     // 1048576 bf16
  bf16*  Aswap = Aneg + 1048576;                     // 1048576 bf16
  float* CCd   = (float*)(Aswap + 1048576);          // 32*64*512 fp32 (4 MB)
  // tail after buf0:
  float* TwP   = f + NBIG;                           // 131072 f
  float* TbF   = TwP + 131072;                       // 131072 f
  float* TbD   = TbF + 131072;                       // 131072 f
  bf16*  Wibf  = (bf16*)(TbD + 131072);              // 262144 bf16 x3
  bf16*  W1bf  = Wibf + 262144;
  bf16*  W2bf  = W1bf + 262144;
  float* meanb = (float*)(W2bf + 262144);
  float* rstdb = meanb + L_;

  // d_out double-duty: [xbf | qbf] -> [xbf | xrbf] -> [y1bf | xrbf]
  bf16* xbf  = (bf16*)d_out;
  bf16* qbf  = xbf + NBIG;
  bf16* xrbf = ((bf16*)d_out) + NBIG;
  bf16* y1bf = (bf16*)d_out;

  // tables + dtype conversions (weights first; x conversion)
  genTwP<<<512, 256, 0, stream>>>(TwP);
  genTbF<<<512, 256, 0, stream>>>(TbF);
  genTbD<<<512, 256, 0, stream>>>(TbF, TbD);
  f2bfK<<<256, 256, 0, stream>>>((const float4*)W_in, (ushort4*)Wibf, 65536);
  f2bfK<<<256, 256, 0, stream>>>((const float4*)W_c1, (ushort4*)W1bf, 65536);
  f2bfK<<<256, 256, 0, stream>>>((const float4*)W_c2, (ushort4*)W2bf, 65536);
  f2bfK<<<256, 256, 0, stream>>>((const float4*)W_out, (ushort4*)Woutbf, 65536);
  twWf<<<4096, 256, 0, stream>>>(Wf_r, Wf_i, WfmR, WfmI);

  // fold W_out into Wf -> Wcat[m][d][0:512]=R, [512:1024]=I
  gemm_bt<false, false, false, true, false, 0, false>
      <<<dim3(4, 4, 32), 256, 0, stream>>>(
      Woutbf, WfmR, nullptr, nullptr, Wcat, 512, 512, 512,
      0, 262144, 524288, 1024, 0);
  gemm_bt<false, false, false, true, false, 0, false>
      <<<dim3(4, 4, 32), 256, 0, stream>>>(
      Woutbf, WfmI, nullptr, nullptr, Wcat, 512, 512, 512,
      0, 262144, 524288, 1024, 512);

  // x -> bf16
  f2bfK<<<2048, 256, 0, stream>>>((const float4*)x, (ushort4*)xbf, NBIG / 4);

  // A: q = x @ W_in^T + b_in  (bf16 out)
  gemm_bt<false, false, true, true, false, 0, false>
      <<<dim3(512, 4, 1), 256, 0, stream>>>(
      xbf, Wibf, b_in, nullptr, qbf, BLROWS, D_, D_, 0, 0, 0, D_, 0);

  // B: forward DFT partials + reduce/pack
  stageB<<<dim3(B_, 8, 8), 256, 0, stream>>>(qbf, TwP, XFp_r, XFp_i);
  reduceXFT<<<dim3(B_, 8), 256, 0, stream>>>(XFp_r, XFp_i, Aneg, Aswap);

  // CC GEMMs: Re(G), Im(G) -> scaled fp32 CCd[b][j][d]
  gemm_bt<false, false, false, false, true, 1, false>
      <<<dim3(1, 4, 32), 256, 0, stream>>>(
      Aneg, Wcat, nullptr, nullptr, CCd, 32, 512, 1024,
      32768, 524288, 0, 0, 0);
  gemm_bt<false, false, false, false, true, 2, false>
      <<<dim3(1, 4, 32), 256, 0, stream>>>(
      Aswap, Wcat, nullptr, nullptr, CCd, 32, 512, 1024,
      32768, 524288, 0, 0, 0);

  // DE (fused): xr = (x - MA(x)) + TbD @ CCd  -> xrbf (qbf dead)
  stageDE<<<dim3(B_, 16), 512, 0, stream>>>(x, TbD, CCd, xrbf);

  // F1: y1 = gelu(xr @ Wc1^T)  (bf16 out, overwrites xbf)
  gemm_bt<true, false, false, true, false, 0, false>
      <<<dim3(512, 4, 1), 256, 0, stream>>>(
      xrbf, W1bf, nullptr, nullptr, y1bf, BLROWS, D_, D_, 0, 0, 0, D_, 0);

  // F2: res = xr + y1 @ Wc2^T  (fp32 -> buf0; resid read as bf16)
  gemm_bt<false, true, false, false, false, 0, true>
      <<<dim3(512, 4, 1), 256, 0, stream>>>(
      y1bf, W2bf, nullptr, (const float*)xrbf, buf0, BLROWS, D_, D_,
      0, 0, 0, D_, 0);

  // G: BatchNorm over (b, d) per l
  bnStats<<<L_, 256, 0, stream>>>(buf0, meanb, rstdb);
  bnApply<<<(NBIG / 4 + 255) / 256, 256, 0, stream>>>(buf0, gamma, beta, meanb,
                                                      rstdb, outp);
}